// Round 8
// baseline (126.706 us; speedup 1.0000x reference)
//
#include <hip/hip_runtime.h>

#define N 4096
#define D 256
#define BT 128
#define NB2 32             // N/BT tiles per dim
#define TRI 528            // NB2*(NB2+1)/2
#define TOTAL 2080         // TRI + TRI + NB2*NB2
#define BK 32              // K-step (halves)
#define KT (D / BK)        // 8 K-steps

typedef __attribute__((ext_vector_type(8))) _Float16 f16x8;
typedef __attribute__((ext_vector_type(4))) _Float16 f16x4;
typedef __attribute__((ext_vector_type(4))) float f32x4;

__device__ __forceinline__ void gld_lds16(const void* g, void* l) {
    __builtin_amdgcn_global_load_lds(
        (const __attribute__((address_space(1))) unsigned int*)g,
        (__attribute__((address_space(3))) unsigned int*)l, 16, 0, 0);
}

// ---- K1: fp32 -> fp16 convert + row squared norms + column-sum partials ----
// Column sums via per-block LDS reduce -> 256 atomicAdds/block. cs is zeroed
// by the hipMemsetAsync node BEFORE this kernel (ordering-safe; the round-6
// in-kernel zeroing raced with other blocks' atomics).
__global__ void k_cvt(const float* __restrict__ x, const float* __restrict__ y,
                      _Float16* __restrict__ xc, _Float16* __restrict__ yc,
                      float* __restrict__ sq, double* __restrict__ cs) {
    const int mat = blockIdx.y;
    const float* src = mat ? y : x;
    _Float16* dst = mat ? yc : xc;
    const int w = threadIdx.x >> 6, lane = threadIdx.x & 63;
    const int r0 = blockIdx.x * 32 + w * 8;
    __shared__ float lds[4][256];
    float4 colacc = {0.f, 0.f, 0.f, 0.f};
    #pragma unroll
    for (int r = 0; r < 8; ++r) {
        const int row = r0 + r;
        const float4 v = *(const float4*)(src + (size_t)row * D + lane * 4);
        f16x4 h;
        h.x = (_Float16)v.x; h.y = (_Float16)v.y;
        h.z = (_Float16)v.z; h.w = (_Float16)v.w;
        *(f16x4*)(dst + (size_t)row * D + lane * 4) = h;
        float s = v.x * v.x + v.y * v.y + v.z * v.z + v.w * v.w;
        #pragma unroll
        for (int off = 32; off; off >>= 1) s += __shfl_down(s, off);
        if (lane == 0) sq[mat * N + row] = s;
        colacc.x += v.x; colacc.y += v.y; colacc.z += v.z; colacc.w += v.w;
    }
    *(float4*)&lds[w][lane * 4] = colacc;
    __syncthreads();
    const int t = threadIdx.x;   // column
    const float part = lds[0][t] + lds[1][t] + lds[2][t] + lds[3][t];
    atomicAdd(&cs[mat * D + t], (double)part);
}

// ---- K2: all three Gram passes in one dispatch. fp16 MFMA (K=256), BK=32
// double-buffered LDS with COUNTED-vmcnt 2-phase pipeline (never drains to 0
// mid-loop), chunk-XOR swizzle via pre-swizzled global source, per-wave
// redundant bandwidth-coefficient prep (kills the k_prep graph node),
// factored single-exp 5-bandwidth epilogue. ----
__global__ __launch_bounds__(256) void k_mmd(
    const _Float16* __restrict__ xc, const _Float16* __restrict__ yc,
    const float* __restrict__ sq, const double* __restrict__ cs,
    double* __restrict__ acc) {
    __shared__ __align__(16) _Float16 As[2 * BT * BK];   // 2 x 8 KB
    __shared__ __align__(16) _Float16 Bs[2 * BT * BK];   // 2 x 8 KB
    __shared__ double red[4];

    const int bid = blockIdx.x;  // no XCD swizzle: 4 MB working set is L2-fit

    // pass decode: 0 = xx (tri), 1 = yy (tri), 2 = xy (full)
    int p, b;
    if (bid < TRI)          { p = 0; b = bid; }
    else if (bid < 2 * TRI) { p = 1; b = bid - TRI; }
    else                    { p = 2; b = bid - 2 * TRI; }
    const _Float16* A = (p == 1) ? yc : xc;
    const _Float16* B = (p == 0) ? xc : yc;
    const float* sqA = (p == 1) ? sq + N : sq;
    const float* sqB = (p == 0) ? sq : sq + N;

    int bi, bj;
    if (p < 2) {  // upper-triangular decode (bi <= bj)
        int rem = b, r = 0;
        while (rem >= NB2 - r) { rem -= NB2 - r; ++r; }
        bi = r; bj = r + rem;
    } else { bi = b >> 5; bj = b & 31; }

    const int tid = threadIdx.x;
    const int lane = tid & 63, w = tid >> 6;

    // --- staging addressing: thread t fills LDS slot t*16 (+4096 per call) ---
    const int srow = tid >> 2;
    const int sc = (tid & 3) ^ (srow & 3) ^ ((srow >> 2) & 3);
    const char* gA = (const char*)A + (size_t)(bi * BT + srow) * (D * 2) + sc * 16;
    const char* gB = (const char*)B + (size_t)(bj * BT + srow) * (D * 2) + sc * 16;
    char* lA = (char*)As + tid * 16;
    char* lB = (char*)Bs + tid * 16;

#define STAGE(kt, buf) do { \
        const int kb_ = (kt) * (BK * 2); const int co_ = (buf) * 8192; \
        gld_lds16(gA + kb_, lA + co_); \
        gld_lds16(gA + kb_ + 64 * (D * 2), lA + co_ + 4096); \
        gld_lds16(gB + kb_, lB + co_); \
        gld_lds16(gB + kb_ + 64 * (D * 2), lB + co_ + 4096); \
    } while (0)

    // prologue: get the first two K-steps' loads in flight immediately
    STAGE(0, 0);
    STAGE(1, 1);

    // --- per-wave redundant coef prep (no barrier; hidden under staging) ---
    // Terms are u^(2^(4-k)) with u = exp2(-d2*c4), c4 = L2E/(16*bw + eps).
    float c4;
    {
        double sx = 0, sy = 0;
        for (int i = lane * 4; i < N; i += 256) {
            const float4 a = *(const float4*)(sq + i);
            const float4 c = *(const float4*)(sq + N + i);
            sx += (double)a.x + (double)a.y + (double)a.z + (double)a.w;
            sy += (double)c.x + (double)c.y + (double)c.z + (double)c.w;
        }
        double cxx = 0, cyy = 0, cxy = 0;
        for (int j = lane; j < D; j += 64) {
            const double cx = cs[j], cy = cs[D + j];
            cxx += cx * cx; cyy += cy * cy; cxy += cx * cy;
        }
        #pragma unroll
        for (int off = 32; off; off >>= 1) {
            sx += __shfl_xor(sx, off);  sy += __shfl_xor(sy, off);
            cxx += __shfl_xor(cxx, off); cyy += __shfl_xor(cyy, off);
            cxy += __shfl_xor(cxy, off);
        }
        const double ns = 2.0 * N;
        const double denom = ns * ns - ns;
        double sd;
        if (p == 0)      sd = 2.0 * N * sx - 2.0 * cxx;
        else if (p == 1) sd = 2.0 * N * sy - 2.0 * cyy;
        else             sd = (double)N * sx + (double)N * sy - 2.0 * cxy;
        const double bw = sd / denom / 4.0;
        c4 = (float)(1.4426950408889634 / (16.0 * bw + 1e-5));
    }
    asm volatile("" : "+v"(c4));              // force prep chain consumed here
    __builtin_amdgcn_sched_barrier(0);        // pin: no prep loads sink below

    // --- fragment read addressing ---
    const int wr = (w >> 1) * 64, wc = (w & 1) * 64;   // wave quadrant
    const int fr = lane & 15;
    const int lg = lane >> 4;                          // k-chunk within MFMA
    const int ch = (lg ^ (fr & 3) ^ (fr >> 2)) * 16;   // XOR-swizzled chunk
    const char* rA = (const char*)As + (wr + fr) * 64 + ch;
    const char* rB = (const char*)Bs + (wc + fr) * 64 + ch;

    f32x4 accv[4][4];
    #pragma unroll
    for (int m = 0; m < 4; ++m)
        #pragma unroll
        for (int n = 0; n < 4; ++n) accv[m][n] = {0.f, 0.f, 0.f, 0.f};

    #pragma unroll
    for (int kt = 0; kt < KT; ++kt) {
        // my stage(kt) landed; stage(kt+1)'s 4 insts may remain in flight
        if (kt < KT - 1) asm volatile("s_waitcnt vmcnt(4)" ::: "memory");
        else             asm volatile("s_waitcnt vmcnt(0)" ::: "memory");
        __builtin_amdgcn_s_barrier();          // everyone's stage(kt) landed
        __builtin_amdgcn_sched_barrier(0);
        const int co = (kt & 1) * 8192;
        f16x8 af[4], bf[4];
        #pragma unroll
        for (int m = 0; m < 4; ++m)
            af[m] = *(const f16x8*)(rA + co + m * 1024);
        #pragma unroll
        for (int n = 0; n < 4; ++n)
            bf[n] = *(const f16x8*)(rB + co + n * 1024);
        #pragma unroll
        for (int m = 0; m < 4; ++m)
            #pragma unroll
            for (int n = 0; n < 4; ++n)
                accv[m][n] = __builtin_amdgcn_mfma_f32_16x16x32_f16(
                    af[m], bf[n], accv[m][n], 0, 0, 0);
        asm volatile("s_waitcnt lgkmcnt(0)" ::: "memory");  // my reads done
        __builtin_amdgcn_s_barrier();          // all reads of buf done
        __builtin_amdgcn_sched_barrier(0);
        if (kt + 2 < KT) STAGE(kt + 2, kt & 1);  // safe to overwrite
    }

    // --- epilogue: arg = -d2*c4 (clamped <= 0); u = exp2(arg);
    //     sum over 5 bandwidths = u + u^2 + u^4 + u^8 + u^16 ---
    const float c2x = 2.f * c4;
    const int row0 = bi * BT + wr + lg * 4;            // C/D: row=(l>>4)*4+reg
    const int col0 = bj * BT + wc + fr;                // C/D: col=l&15
    float asa[4][4], bsb[4];
    #pragma unroll
    for (int m = 0; m < 4; ++m) {
        const f32x4 sa = *(const f32x4*)(sqA + row0 + m * 16);
        #pragma unroll
        for (int i = 0; i < 4; ++i) asa[m][i] = sa[i] * c4;
    }
    #pragma unroll
    for (int n = 0; n < 4; ++n) bsb[n] = sqB[col0 + n * 16] * c4;
    float s = 0.f;
    #pragma unroll
    for (int m = 0; m < 4; ++m)
        #pragma unroll
        for (int n = 0; n < 4; ++n)
            #pragma unroll
            for (int i = 0; i < 4; ++i) {
                float arg = fmaf(accv[m][n][i], c2x, -(asa[m][i] + bsb[n]));
                arg = fminf(arg, 0.f);                 // d2 >= 0 clamp
                const float u = __builtin_amdgcn_exp2f(arg);
                const float u2 = u * u, u4 = u2 * u2;
                const float u8 = u4 * u4, u16 = u8 * u8;
                s += (u + u2) + (u4 + u8) + u16;
            }
    if (p < 2 && bi != bj) s *= 2.f;   // triangular symmetry weight

    double sd = (double)s;
    #pragma unroll
    for (int off = 32; off; off >>= 1) sd += __shfl_down(sd, off);
    if (lane == 0) red[w] = sd;
    __syncthreads();
    if (tid == 0) atomicAdd(&acc[p], red[0] + red[1] + red[2] + red[3]);
#undef STAGE
}

// ---- K3: combine ----
__global__ void k_final(const double* __restrict__ acc, float* __restrict__ out) {
    const double inv = 1.0 / ((double)N * (double)N);
    out[0] = (float)((acc[0] + acc[1] - 2.0 * acc[2]) * inv);
}

extern "C" void kernel_launch(void* const* d_in, const int* in_sizes, int n_in,
                              void* d_out, int out_size, void* d_ws, size_t ws_size,
                              hipStream_t stream) {
    const float* x = (const float*)d_in[0];
    const float* y = (const float*)d_in[1];
    float* out = (float*)d_out;

    double* wsd = (double*)d_ws;
    double* acc = wsd;                        // 3 doubles (zeroed by memset)
    double* cs  = wsd + 8;                    // 512 doubles (zeroed by memset)
    float*  sq  = (float*)(wsd + 520);        // 8192 floats
    char* base = (char*)d_ws;
    _Float16* xc = (_Float16*)(base + 40960);                       // 2 MB
    _Float16* yc = (_Float16*)(base + 40960 + (size_t)N * D * 2);   // 2 MB

    hipMemsetAsync(wsd, 0, 520 * sizeof(double), stream);
    k_cvt<<<dim3(N / 32, 2), 256, 0, stream>>>(x, y, xc, yc, sq, cs);
    k_mmd<<<TOTAL, 256, 0, stream>>>(xc, yc, sq, cs, acc);
    k_final<<<1, 1, 0, stream>>>(acc, out);
}

// Round 9
// 119.691 us; speedup vs baseline: 1.0586x; 1.0586x over previous
//
#include <hip/hip_runtime.h>

#define N 4096
#define D 256
#define BT 128
#define NB2 32             // N/BT tiles per dim
#define TRI 528            // NB2*(NB2+1)/2
#define TOTAL 2080         // TRI + TRI + NB2*NB2
#define BK 32              // K-step (halves)
#define KT (D / BK)        // 8 K-steps

typedef __attribute__((ext_vector_type(8))) _Float16 f16x8;
typedef __attribute__((ext_vector_type(4))) _Float16 f16x4;
typedef __attribute__((ext_vector_type(4))) float f32x4;

__device__ __forceinline__ void gld_lds16(const void* g, void* l) {
    __builtin_amdgcn_global_load_lds(
        (const __attribute__((address_space(1))) unsigned int*)g,
        (__attribute__((address_space(3))) unsigned int*)l, 16, 0, 0);
}

// ---- K1: fp32 -> fp16 convert + row squared norms + PER-BLOCK column
// partial sums (plain stores to distinct slots: no atomics, no memset). ----
__global__ void k_cvt(const float* __restrict__ x, const float* __restrict__ y,
                      _Float16* __restrict__ xc, _Float16* __restrict__ yc,
                      float* __restrict__ sq, float* __restrict__ pb) {
    const int mat = blockIdx.y;
    const float* src = mat ? y : x;
    _Float16* dst = mat ? yc : xc;
    const int w = threadIdx.x >> 6, lane = threadIdx.x & 63;
    const int r0 = blockIdx.x * 32 + w * 8;
    __shared__ float lds[4][256];
    float4 colacc = {0.f, 0.f, 0.f, 0.f};
    #pragma unroll
    for (int r = 0; r < 8; ++r) {
        const int row = r0 + r;
        const float4 v = *(const float4*)(src + (size_t)row * D + lane * 4);
        f16x4 h;
        h.x = (_Float16)v.x; h.y = (_Float16)v.y;
        h.z = (_Float16)v.z; h.w = (_Float16)v.w;
        *(f16x4*)(dst + (size_t)row * D + lane * 4) = h;
        float s = v.x * v.x + v.y * v.y + v.z * v.z + v.w * v.w;
        #pragma unroll
        for (int off = 32; off; off >>= 1) s += __shfl_down(s, off);
        if (lane == 0) sq[mat * N + row] = s;
        colacc.x += v.x; colacc.y += v.y; colacc.z += v.z; colacc.w += v.w;
    }
    *(float4*)&lds[w][lane * 4] = colacc;
    __syncthreads();
    const int t = threadIdx.x;   // column
    pb[(mat * (N / 32) + blockIdx.x) * 256 + t] =
        lds[0][t] + lds[1][t] + lds[2][t] + lds[3][t];
}

// ---- K2: reduce partials -> closed-form sum(d2) -> coefs; zero acc ----
// Terms are u^(2^(4-k)) with u = exp2(-d2*c4), c4 = L2E/(16*bw + eps).
__global__ void k_prep(const float* __restrict__ sq, const float* __restrict__ pb,
                       float* __restrict__ coef, double* __restrict__ acc) {
    const int t = threadIdx.x;  // 256 = column
    double sx = 0, sy = 0;
    for (int i = t; i < N; i += 256) { sx += (double)sq[i]; sy += (double)sq[N + i]; }
    double cx = 0, cy = 0;
    for (int b = 0; b < N / 32; ++b) {
        cx += (double)pb[b * 256 + t];
        cy += (double)pb[(N / 32 + b) * 256 + t];
    }
    double v[5] = {sx, sy, cx * cx, cy * cy, cx * cy};
    #pragma unroll
    for (int k = 0; k < 5; ++k)
        for (int off = 32; off; off >>= 1) v[k] += __shfl_down(v[k], off);
    __shared__ double red[4][5];
    const int w = t >> 6, lane = t & 63;
    if (lane == 0) for (int k = 0; k < 5; ++k) red[w][k] = v[k];
    __syncthreads();
    if (t == 0) {
        double Sx = 0, Sy = 0, Cxx = 0, Cyy = 0, Cxy = 0;
        for (int q = 0; q < 4; ++q) {
            Sx += red[q][0]; Sy += red[q][1];
            Cxx += red[q][2]; Cyy += red[q][3]; Cxy += red[q][4];
        }
        const double ns = 2.0 * N;
        const double denom = ns * ns - ns;
        const double sd[3] = {
            2.0 * N * Sx - 2.0 * Cxx,
            2.0 * N * Sy - 2.0 * Cyy,
            (double)N * Sx + (double)N * Sy - 2.0 * Cxy };
        const double L2E = 1.4426950408889634;
        for (int q = 0; q < 3; ++q) {
            const double bw = sd[q] / denom / 4.0;
            coef[q] = (float)(L2E / (16.0 * bw + 1e-5));
        }
        acc[0] = 0.0; acc[1] = 0.0; acc[2] = 0.0;
    }
}

// ---- K3: all three Gram passes in one dispatch. fp16 MFMA (K=256), BK=32
// double-buffered LDS, T3-minimum pipeline: STAGE(next) at iteration TOP
// (hides under ds_read+MFMA), ONE vmcnt(0)+s_barrier per K-step. Chunk-XOR
// swizzle via pre-swizzled global source; factored single-exp epilogue. ----
__global__ __launch_bounds__(256) void k_mmd(
    const _Float16* __restrict__ xc, const _Float16* __restrict__ yc,
    const float* __restrict__ sq, const float* __restrict__ coefs,
    double* __restrict__ acc) {
    __shared__ __align__(16) _Float16 As[2 * BT * BK];   // 2 x 8 KB
    __shared__ __align__(16) _Float16 Bs[2 * BT * BK];   // 2 x 8 KB
    __shared__ double red[4];

    // XCD-aware swizzle (TOTAL % 8 == 0): neighboring tiles share an XCD L2
    const int bid = (blockIdx.x & 7) * (TOTAL / 8) + (blockIdx.x >> 3);

    // pass decode: 0 = xx (tri), 1 = yy (tri), 2 = xy (full)
    int p, b;
    if (bid < TRI)          { p = 0; b = bid; }
    else if (bid < 2 * TRI) { p = 1; b = bid - TRI; }
    else                    { p = 2; b = bid - 2 * TRI; }
    const _Float16* A = (p == 1) ? yc : xc;
    const _Float16* B = (p == 0) ? xc : yc;
    const float* sqA = (p == 1) ? sq + N : sq;
    const float* sqB = (p == 0) ? sq : sq + N;
    const float c4 = coefs[p];

    int bi, bj;
    if (p < 2) {  // upper-triangular decode (bi <= bj)
        int rem = b, r = 0;
        while (rem >= NB2 - r) { rem -= NB2 - r; ++r; }
        bi = r; bj = r + rem;
    } else { bi = b >> 5; bj = b & 31; }

    const int tid = threadIdx.x;
    const int lane = tid & 63, w = tid >> 6;

    // --- staging: thread t fills LDS slot t*16 (+4096 per call) ---
    // LDS row = q*64 + (t>>2), pos = t&3; LDS[row][pos] holds global chunk
    // pos ^ f(row), f(row) = (row ^ (row>>2)) & 3.
    const int srow = tid >> 2;
    const int sc = (tid & 3) ^ (srow & 3) ^ ((srow >> 2) & 3);
    const char* gA = (const char*)A + (size_t)(bi * BT + srow) * (D * 2) + sc * 16;
    const char* gB = (const char*)B + (size_t)(bj * BT + srow) * (D * 2) + sc * 16;
    char* lA = (char*)As + tid * 16;
    char* lB = (char*)Bs + tid * 16;

#define STAGE(kt, buf) do { \
        const int kb_ = (kt) * (BK * 2); const int co_ = (buf) * 8192; \
        gld_lds16(gA + kb_, lA + co_); \
        gld_lds16(gA + kb_ + 64 * (D * 2), lA + co_ + 4096); \
        gld_lds16(gB + kb_, lB + co_); \
        gld_lds16(gB + kb_ + 64 * (D * 2), lB + co_ + 4096); \
    } while (0)

    // --- fragment read addressing ---
    const int wr = (w >> 1) * 64, wc = (w & 1) * 64;   // wave quadrant
    const int fr = lane & 15;
    const int lg = lane >> 4;                          // k-chunk within MFMA
    const int ch = (lg ^ (fr & 3) ^ (fr >> 2)) * 16;   // XOR-swizzled chunk
    const char* rA = (const char*)As + (wr + fr) * 64 + ch;
    const char* rB = (const char*)Bs + (wc + fr) * 64 + ch;

    f32x4 accv[4][4];
    #pragma unroll
    for (int m = 0; m < 4; ++m)
        #pragma unroll
        for (int n = 0; n < 4; ++n) accv[m][n] = {0.f, 0.f, 0.f, 0.f};

    // prologue: stage K-step 0, drain, barrier
    STAGE(0, 0);
    asm volatile("s_waitcnt vmcnt(0)" ::: "memory");
    __builtin_amdgcn_s_barrier();
    __builtin_amdgcn_sched_barrier(0);

    #pragma unroll
    for (int kt = 0; kt < KT; ++kt) {
        if (kt + 1 < KT) STAGE(kt + 1, (kt + 1) & 1);   // hides under compute
        const int co = (kt & 1) * 8192;
        f16x8 af[4], bf[4];
        #pragma unroll
        for (int m = 0; m < 4; ++m)
            af[m] = *(const f16x8*)(rA + co + m * 1024);
        #pragma unroll
        for (int n = 0; n < 4; ++n)
            bf[n] = *(const f16x8*)(rB + co + n * 1024);
        asm volatile("s_waitcnt lgkmcnt(0)" ::: "memory");  // my reads done
        __builtin_amdgcn_sched_barrier(0);                  // rule 18: pin MFMA
        #pragma unroll
        for (int m = 0; m < 4; ++m)
            #pragma unroll
            for (int n = 0; n < 4; ++n)
                accv[m][n] = __builtin_amdgcn_mfma_f32_16x16x32_f16(
                    af[m], bf[n], accv[m][n], 0, 0, 0);
        if (kt + 1 < KT) {
            // one barrier per K-step: everyone's reads done (lgkm above) and
            // everyone's STAGE(kt+1) landed -> safe to read buf^1 next iter
            asm volatile("s_waitcnt vmcnt(0)" ::: "memory");
            __builtin_amdgcn_s_barrier();
            __builtin_amdgcn_sched_barrier(0);
        }
    }

    // --- epilogue: arg = -d2*c4 (clamped <= 0); u = exp2(arg);
    //     sum over 5 bandwidths = u + u^2 + u^4 + u^8 + u^16 ---
    const float c2x = 2.f * c4;
    const int row0 = bi * BT + wr + lg * 4;            // C/D: row=(l>>4)*4+reg
    const int col0 = bj * BT + wc + fr;                // C/D: col=l&15
    float asa[4][4], bsb[4];
    #pragma unroll
    for (int m = 0; m < 4; ++m) {
        const f32x4 sa = *(const f32x4*)(sqA + row0 + m * 16);
        #pragma unroll
        for (int i = 0; i < 4; ++i) asa[m][i] = sa[i] * c4;
    }
    #pragma unroll
    for (int n = 0; n < 4; ++n) bsb[n] = sqB[col0 + n * 16] * c4;
    float s = 0.f;
    #pragma unroll
    for (int m = 0; m < 4; ++m)
        #pragma unroll
        for (int n = 0; n < 4; ++n)
            #pragma unroll
            for (int i = 0; i < 4; ++i) {
                float arg = fmaf(accv[m][n][i], c2x, -(asa[m][i] + bsb[n]));
                arg = fminf(arg, 0.f);                 // d2 >= 0 clamp
                const float u = __builtin_amdgcn_exp2f(arg);
                const float u2 = u * u, u4 = u2 * u2;
                const float u8 = u4 * u4, u16 = u8 * u8;
                s += (u + u2) + (u4 + u8) + u16;
            }
    if (p < 2 && bi != bj) s *= 2.f;   // triangular symmetry weight

    double sd = (double)s;
    #pragma unroll
    for (int off = 32; off; off >>= 1) sd += __shfl_down(sd, off);
    if (lane == 0) red[w] = sd;
    __syncthreads();
    if (tid == 0) atomicAdd(&acc[p], red[0] + red[1] + red[2] + red[3]);
#undef STAGE
}

// ---- K4: combine ----
__global__ void k_final(const double* __restrict__ acc, float* __restrict__ out) {
    const double inv = 1.0 / ((double)N * (double)N);
    out[0] = (float)((acc[0] + acc[1] - 2.0 * acc[2]) * inv);
}

extern "C" void kernel_launch(void* const* d_in, const int* in_sizes, int n_in,
                              void* d_out, int out_size, void* d_ws, size_t ws_size,
                              hipStream_t stream) {
    const float* x = (const float*)d_in[0];
    const float* y = (const float*)d_in[1];
    float* out = (float*)d_out;

    char* base = (char*)d_ws;
    double* acc = (double*)base;                    // 3 doubles (zeroed in k_prep)
    float*  sq  = (float*)(base + 64);              // 2*4096 floats (32 KB)
    float*  coef = (float*)(base + 64 + 32768);     // 3 floats
    float*  pb  = (float*)(base + 65536);           // 2*128*256 floats (256 KB)
    _Float16* xc = (_Float16*)(base + 65536 + 262144);              // 2 MB
    _Float16* yc = (_Float16*)(base + 65536 + 262144 + N * D * 2);  // 2 MB

    k_cvt<<<dim3(N / 32, 2), 256, 0, stream>>>(x, y, xc, yc, sq, pb);
    k_prep<<<1, 256, 0, stream>>>(sq, pb, coef, acc);
    k_mmd<<<TOTAL, 256, 0, stream>>>(xc, yc, sq, coef, acc);
    k_final<<<1, 1, 0, stream>>>(acc, out);
}